// Round 9
// baseline (357.095 us; speedup 1.0000x reference)
//
#include <hip/hip_runtime.h>

// Analysis filters
__device__ __constant__ float H0[8] = { 0.0322231f, -0.01260397f, -0.09921954f,  0.2978578f,
                                        0.80373875f, 0.49761867f, -0.02963553f, -0.07576571f};
__device__ __constant__ float H1[8] = { 0.07576571f, -0.02963553f, -0.49761867f, 0.80373875f,
                                       -0.2978578f, -0.09921954f,  0.01260397f,  0.0322231f};
// Synthesis filters g0 = reverse(h0), g1 = reverse(h1)
__device__ __constant__ float G0[8] = {-0.07576571f, -0.02963553f,  0.49761867f, 0.80373875f,
                                        0.2978578f,  -0.09921954f, -0.01260397f, 0.0322231f};
__device__ __constant__ float G1[8] = { 0.0322231f,   0.01260397f, -0.09921954f, -0.2978578f,
                                        0.80373875f, -0.49761867f, -0.02963553f, 0.07576571f};

// ---------------------------------------------------------------------------
// Forward DWT, 2x2-output-tiled + separable (unchanged).
// ---------------------------------------------------------------------------
template<int HIN>
__global__ __launch_bounds__(256) void fwd_dwt(const float* __restrict__ in,
                                               float* __restrict__ oLL, float* __restrict__ oLH,
                                               float* __restrict__ oHL, float* __restrict__ oHH)
{
    constexpr int OH = HIN / 2;
    constexpr int TQ = OH / 2;
    const int tid = threadIdx.x;
    const int c = tid & 63;
    const int s = blockIdx.x * 4 + (tid >> 6);
    const int j = s % TQ;
    const int i = (s / TQ) % TQ;
    const int b = s / (TQ * TQ);

    float acc[2][2][4];
#pragma unroll
    for (int a = 0; a < 2; ++a)
#pragma unroll
        for (int d = 0; d < 2; ++d)
#pragma unroll
            for (int k = 0; k < 4; ++k) acc[a][d][k] = 0.f;

    const int iw0 = 4 * j - 3;
#pragma unroll
    for (int r = 0; r < 10; ++r) {
        const int ih = 4 * i + r - 3;
        if ((unsigned)ih < (unsigned)HIN) {
            const float* row = in + ((b * HIN + ih) * HIN) * 64 + c;
            float xv[10];
#pragma unroll
            for (int v = 0; v < 10; ++v) {
                const int iw = iw0 + v;
                xv[v] = ((unsigned)iw < (unsigned)HIN) ? row[iw * 64] : 0.f;
            }
            float h00 = 0.f, h01 = 0.f, h10 = 0.f, h11 = 0.f;
#pragma unroll
            for (int v = 0; v < 8; ++v) {
                h00 += H0[v] * xv[v];
                h10 += H1[v] * xv[v];
                h01 += H0[v] * xv[v + 2];
                h11 += H1[v] * xv[v + 2];
            }
#pragma unroll
            for (int ii = 0; ii < 2; ++ii) {
                const int u = r - 2 * ii;
                if (0 <= u && u < 8) {
                    const float a0 = H0[u], a1 = H1[u];
                    acc[ii][0][0] += a0 * h00;
                    acc[ii][0][1] += a0 * h10;
                    acc[ii][0][2] += a1 * h00;
                    acc[ii][0][3] += a1 * h10;
                    acc[ii][1][0] += a0 * h01;
                    acc[ii][1][1] += a0 * h11;
                    acc[ii][1][2] += a1 * h01;
                    acc[ii][1][3] += a1 * h11;
                }
            }
        }
    }

#pragma unroll
    for (int ii = 0; ii < 2; ++ii)
#pragma unroll
        for (int jj = 0; jj < 2; ++jj) {
            const int oh = 2 * i + ii, ow = 2 * j + jj;
            const int oidx = ((b * OH + oh) * OH + ow) * 64 + c;
            oLL[oidx] = acc[ii][jj][0];
            oLH[oidx] = acc[ii][jj][1];
            oHL[oidx] = acc[ii][jj][2];
            oHH[oidx] = acc[ii][jj][3];
        }
}

// ---------------------------------------------------------------------------
// Activation transpose: t[b,h,w,i] -> A'[w][i][b][h] (unchanged).
// ---------------------------------------------------------------------------
template<int HD>
__global__ __launch_bounds__(256) void act_tr(const float* __restrict__ in,
                                              float* __restrict__ outp)
{
    __shared__ float Ld[64][HD + 1];
    const int w = blockIdx.x;
    const int b = blockIdx.y;
    const int t = threadIdx.x;

    {   // read: lane = i (dense 256B per (b,h,w))
        const int i = t & 63;
        const int hq = t >> 6;
#pragma unroll
        for (int s = 0; s < HD / 4; ++s) {
            const int h = hq * (HD / 4) + s;
            Ld[i][h] = in[((size_t)(b * HD + h) * HD + w) * 64 + i];
        }
    }
    __syncthreads();
    {   // write: lane = h (dense per (w,i,b))
        const int h = t & (HD - 1);
        const int iq = t / HD;
        constexpr int NIQ = 256 / HD;
#pragma unroll
        for (int s = 0; s < 64 / NIQ; ++s) {
            const int i = s * NIQ + iq;
            outp[((size_t)(w * 64 + i) * 16 + b) * HD + h] = Ld[i][h];
        }
    }
}

// ---------------------------------------------------------------------------
// Local conv v8: direct-register GEMM, h-split tiles for occupancy.
// out[b,h,w,o] = sum_i A'[w][i][b][h] * W[i,o,w,h]
// Block tile: 32 h x OT o x 16 b at one w. Logical id order:
//   (((z*W + w)*OGN + og)*HG + hg)  -- hg fastest, so the two h-halves of a
// (w,og) panel are ADJACENT and land on the SAME XCD under the bijective
// chunked swizzle -> the two 128B halves of each 256B weight line are
// fetched by one L2 (no HBM duplication).
// Thread = (hc 0..31, r 0..7): acc = 2 b x OT o (~45 VGPR -> high occupancy).
// Epilogue re-layouts through LDS for o-dense full-sector stores.
// ---------------------------------------------------------------------------
template<int HD, int OT>
__global__ __launch_bounds__(256) void local_conv_v8(
    const float* __restrict__ a0, const float* __restrict__ a1,
    const float* __restrict__ a2, const float* __restrict__ a3,
    const float* __restrict__ w0, const float* __restrict__ w1,
    const float* __restrict__ w2, const float* __restrict__ w3,
    float* __restrict__ o0, float* __restrict__ o1,
    float* __restrict__ o2, float* __restrict__ o3)
{
    constexpr int WH   = HD * HD;
    constexpr int HG   = HD / 32;      // h-groups per panel
    constexpr int OGN  = 64 / OT;      // o-groups
    constexpr int PERZ = OGN * HD * HG;
    constexpr int NB   = 2;            // b per thread
    constexpr int NO4  = OT / 4;
    constexpr int NR   = 8;            // r-groups

    __shared__ float E[NB][32][NO4 * 4 + 4];

    // bijective XCD-chunked swizzle (nwg % 8 == 0 for all our grids)
    const int nwg = gridDim.x;
    const int hb  = blockIdx.x;
    const int l   = (hb & 7) * (nwg >> 3) + (hb >> 3);

    const int z   = l / PERZ;
    int rem       = l - z * PERZ;
    const int w   = rem / (OGN * HG);
    rem          -= w * (OGN * HG);
    const int og  = rem / HG;
    const int hg  = rem - og * HG;
    const int hbase = hg * 32;

    const float* act = (z == 0) ? a0 : (z == 1) ? a1 : (z == 2) ? a2 : a3;
    const float* wgt = (z == 0) ? w0 : (z == 1) ? w1 : (z == 2) ? w2 : w3;
    float*       out = (z == 0) ? o0 : (z == 1) ? o1 : (z == 2) ? o2 : o3;

    const int t  = threadIdx.x;
    const int hc = t & 31;
    const int r  = t >> 5;
    const int b0 = r * NB;

    const float* wp = wgt + (size_t)(og * OT) * WH + w * HD + hbase + hc;
    const float* ap = act + ((size_t)(w * 64) * 16 + b0) * HD + hbase + hc;

    float acc[NB][OT];
#pragma unroll
    for (int j = 0; j < NB; ++j)
#pragma unroll
        for (int q = 0; q < OT; ++q) acc[j][q] = 0.f;

    for (int ch = 0; ch < 32; ++ch) {
        const int i0 = ch * 2;
        float wr[2][OT];
        float ar[2][NB];
#pragma unroll
        for (int ii = 0; ii < 2; ++ii) {
#pragma unroll
            for (int q = 0; q < OT; ++q)
                wr[ii][q] = wp[(size_t)((i0 + ii) * 64 + q) * WH];
#pragma unroll
            for (int j = 0; j < NB; ++j)
                ar[ii][j] = ap[(size_t)((i0 + ii) * 16 + j) * HD];
        }
#pragma unroll
        for (int ii = 0; ii < 2; ++ii)
#pragma unroll
            for (int j = 0; j < NB; ++j) {
                const float a = ar[ii][j];
#pragma unroll
                for (int q = 0; q < OT; ++q)
                    acc[j][q] += a * wr[ii][q];
            }
    }

    // ---- epilogue: re-layout through LDS, store o-dense runs ----
    const int oF = t & (NO4 - 1);
    const int h2 = (t / NO4) & 31;
    const int be = t / (NO4 * 32);

    for (int p = 0; p < NR; ++p) {
        if (p) __syncthreads();
        if (r == p) {
#pragma unroll
            for (int j = 0; j < NB; ++j)
#pragma unroll
                for (int q = 0; q < OT; ++q)
                    E[j][hc][q] = acc[j][q];
        }
        __syncthreads();
        if (be < NB) {
            float4 v = *(const float4*)&E[be][h2][oF * 4];
            const int b = p * NB + be;
            *(float4*)(out + ((size_t)(b * HD + hbase + h2) * HD + w) * 64
                       + og * OT + oF * 4) = v;
        }
    }
}

// ---------------------------------------------------------------------------
// Inverse DWT, 2x2-output-tiled + separable (unchanged).
// ---------------------------------------------------------------------------
template<int HOUT>
__global__ __launch_bounds__(256) void inv_dwt(const float* __restrict__ yLL,
                                               const float* __restrict__ yLH,
                                               const float* __restrict__ yHL,
                                               const float* __restrict__ yHH,
                                               float* __restrict__ out)
{
    constexpr int HS = HOUT / 2;
    const int tid = threadIdx.x;
    const int c = tid & 63;
    const int s = blockIdx.x * 4 + (tid >> 6);
    const int j = s % HS;
    const int i = (s / HS) % HS;
    const int b = s / (HS * HS);

    float Pe[4] = {0.f, 0.f, 0.f, 0.f}, Po[4] = {0.f, 0.f, 0.f, 0.f};
    float Qe[4] = {0.f, 0.f, 0.f, 0.f}, Qo[4] = {0.f, 0.f, 0.f, 0.f};

#pragma unroll
    for (int ku = 0; ku < 4; ++ku) {
        const int m = i - 1 + ku;
        if ((unsigned)m < (unsigned)HS) {
            const float a0e = G0[1 + 2 * ku], a0o = G0[2 * ku];
            const float a1e = G1[1 + 2 * ku], a1o = G1[2 * ku];
            const int rowoff = (b * HS + m) * HS;
#pragma unroll
            for (int kv = 0; kv < 4; ++kv) {
                const int n = j - 1 + kv;
                if ((unsigned)n < (unsigned)HS) {
                    const int idx = (rowoff + n) * 64 + c;
                    const float yll = yLL[idx], ylh = yLH[idx];
                    const float yhl = yHL[idx], yhh = yHH[idx];
                    Pe[kv] += a0e * yll + a1e * yhl;
                    Po[kv] += a0o * yll + a1o * yhl;
                    Qe[kv] += a0e * ylh + a1e * yhh;
                    Qo[kv] += a0o * ylh + a1o * yhh;
                }
            }
        }
    }

    float o00 = 0.f, o01 = 0.f, o10 = 0.f, o11 = 0.f;
#pragma unroll
    for (int kv = 0; kv < 4; ++kv) {
        const float b0e = G0[1 + 2 * kv], b0o = G0[2 * kv];
        const float b1e = G1[1 + 2 * kv], b1o = G1[2 * kv];
        o00 += b0e * Pe[kv] + b1e * Qe[kv];
        o01 += b0o * Pe[kv] + b1o * Qe[kv];
        o10 += b0e * Po[kv] + b1e * Qo[kv];
        o11 += b0o * Po[kv] + b1o * Qo[kv];
    }

    const int h0 = 2 * i, w0 = 2 * j;
    const int base = ((b * HOUT + h0) * HOUT + w0) * 64 + c;
    out[base] = o00;
    out[base + 64] = o01;
    out[base + HOUT * 64] = o10;
    out[base + HOUT * 64 + 64] = o11;
}

// ---------------------------------------------------------------------------
extern "C" void kernel_launch(void* const* d_in, const int* in_sizes, int n_in,
                              void* d_out, int out_size, void* d_ws, size_t ws_size,
                              hipStream_t stream)
{
    const float* x    = (const float*)d_in[0];
    const float* wLL  = (const float*)d_in[1];
    const float* wLH0 = (const float*)d_in[2];
    const float* wHL0 = (const float*)d_in[3];
    const float* wHH0 = (const float*)d_in[4];
    const float* wLH1 = (const float*)d_in[5];
    const float* wHL1 = (const float*)d_in[6];
    const float* wHH1 = (const float*)d_in[7];
    float* out = (float*)d_out;
    float* ws  = (float*)d_ws;

    const int S0 = 16 * 64 * 64 * 64;   // level-0 subband elems (4S1 = S0)
    const int S1 = 16 * 32 * 32 * 64;   // level-1 subband elems

    // d_out doubles as scratch: first c0{LL,LH,HL,HH}, then transposed acts.
    float* c0 = out;                    // 4*S0
    float* A0 = out;                    // 3*S0: LH',HL',HH' (reuse dead c0 slots)
    float* A1 = out + 3 * S0;           // 4*S1: LL',LH',HL',HH'

    float* c1 = ws;                     // 4*S1, later reused as r1
    float* t0 = ws + 4 * S1;            // 3*S0
    float* t1 = ws + 4 * S1 + 3 * S0;   // 3*S1
    float* yA = ws + 7 * S1 + 3 * S0;   // S1
    float* r1 = ws;                     // S0, overwrites dead c1

    // 1) level-0 forward DWT: x -> c0 (in d_out)
    fwd_dwt<128><<<16 * 32 * 32 / 4, 256, 0, stream>>>(x, c0, c0 + S0, c0 + 2 * S0, c0 + 3 * S0);

    // 2) level-1 forward DWT: c0LL -> c1 (ws)
    fwd_dwt<64><<<16 * 16 * 16 / 4, 256, 0, stream>>>(c0,
        c1 + 0 * S1, c1 + 1 * S1, c1 + 2 * S1, c1 + 3 * S1);

    // 3) transpose level-0 details into dead c0 slots (sequential chain)
    act_tr<64><<<dim3(64, 16), 256, 0, stream>>>(c0 + 1 * S0, A0 + 0 * S0);  // LH'
    act_tr<64><<<dim3(64, 16), 256, 0, stream>>>(c0 + 2 * S0, A0 + 1 * S0);  // HL'
    act_tr<64><<<dim3(64, 16), 256, 0, stream>>>(c0 + 3 * S0, A0 + 2 * S0);  // HH'

    // 4) transpose level-1 subbands
    act_tr<32><<<dim3(32, 16), 256, 0, stream>>>(c1 + 0 * S1, A1 + 0 * S1);  // LL'
    act_tr<32><<<dim3(32, 16), 256, 0, stream>>>(c1 + 1 * S1, A1 + 1 * S1);  // LH'
    act_tr<32><<<dim3(32, 16), 256, 0, stream>>>(c1 + 2 * S1, A1 + 2 * S1);  // HL'
    act_tr<32><<<dim3(32, 16), 256, 0, stream>>>(c1 + 3 * S1, A1 + 3 * S1);  // HH'

    // 5) local conv level-0: HD=64, OT=16 -> grid 3z*64w*4og*2hg = 1536
    local_conv_v8<64, 16><<<1536, 256, 0, stream>>>(
        A0 + 0 * S0, A0 + 1 * S0, A0 + 2 * S0, nullptr,
        wLH0, wHL0, wHH0, nullptr,
        t0 + 0 * S0, t0 + 1 * S0, t0 + 2 * S0, nullptr);

    // 6) local conv level-1: HD=32, OT=8 -> grid 4z*32w*8og*1hg = 1024
    local_conv_v8<32, 8><<<1024, 256, 0, stream>>>(
        A1 + 1 * S1, A1 + 2 * S1, A1 + 3 * S1, A1 + 0 * S1,
        wLH1, wHL1, wHH1, wLL,
        t1 + 0 * S1, t1 + 1 * S1, t1 + 2 * S1, yA);

    // 7) inverse level-1: (yA, t1) -> r1
    inv_dwt<64><<<16 * 32 * 32 / 4, 256, 0, stream>>>(
        yA, t1 + 0 * S1, t1 + 1 * S1, t1 + 2 * S1, r1);

    // 8) inverse level-0: (r1, t0) -> out
    inv_dwt<128><<<16 * 64 * 64 / 4, 256, 0, stream>>>(
        r1, t0 + 0 * S0, t0 + 1 * S0, t0 + 2 * S0, out);
}

// Round 10
// 326.289 us; speedup vs baseline: 1.0944x; 1.0944x over previous
//
#include <hip/hip_runtime.h>

// Analysis filters
__device__ __constant__ float H0[8] = { 0.0322231f, -0.01260397f, -0.09921954f,  0.2978578f,
                                        0.80373875f, 0.49761867f, -0.02963553f, -0.07576571f};
__device__ __constant__ float H1[8] = { 0.07576571f, -0.02963553f, -0.49761867f, 0.80373875f,
                                       -0.2978578f, -0.09921954f,  0.01260397f,  0.0322231f};
// Synthesis filters g0 = reverse(h0), g1 = reverse(h1)
__device__ __constant__ float G0[8] = {-0.07576571f, -0.02963553f,  0.49761867f, 0.80373875f,
                                        0.2978578f,  -0.09921954f, -0.01260397f, 0.0322231f};
__device__ __constant__ float G1[8] = { 0.0322231f,   0.01260397f, -0.09921954f, -0.2978578f,
                                        0.80373875f, -0.49761867f, -0.02963553f, 0.07576571f};

// ---------------------------------------------------------------------------
// Forward DWT, 2x2-output-tiled + separable (unchanged).
// ---------------------------------------------------------------------------
template<int HIN>
__global__ __launch_bounds__(256) void fwd_dwt(const float* __restrict__ in,
                                               float* __restrict__ oLL, float* __restrict__ oLH,
                                               float* __restrict__ oHL, float* __restrict__ oHH)
{
    constexpr int OH = HIN / 2;
    constexpr int TQ = OH / 2;
    const int tid = threadIdx.x;
    const int c = tid & 63;
    const int s = blockIdx.x * 4 + (tid >> 6);
    const int j = s % TQ;
    const int i = (s / TQ) % TQ;
    const int b = s / (TQ * TQ);

    float acc[2][2][4];
#pragma unroll
    for (int a = 0; a < 2; ++a)
#pragma unroll
        for (int d = 0; d < 2; ++d)
#pragma unroll
            for (int k = 0; k < 4; ++k) acc[a][d][k] = 0.f;

    const int iw0 = 4 * j - 3;
#pragma unroll
    for (int r = 0; r < 10; ++r) {
        const int ih = 4 * i + r - 3;
        if ((unsigned)ih < (unsigned)HIN) {
            const float* row = in + ((b * HIN + ih) * HIN) * 64 + c;
            float xv[10];
#pragma unroll
            for (int v = 0; v < 10; ++v) {
                const int iw = iw0 + v;
                xv[v] = ((unsigned)iw < (unsigned)HIN) ? row[iw * 64] : 0.f;
            }
            float h00 = 0.f, h01 = 0.f, h10 = 0.f, h11 = 0.f;
#pragma unroll
            for (int v = 0; v < 8; ++v) {
                h00 += H0[v] * xv[v];
                h10 += H1[v] * xv[v];
                h01 += H0[v] * xv[v + 2];
                h11 += H1[v] * xv[v + 2];
            }
#pragma unroll
            for (int ii = 0; ii < 2; ++ii) {
                const int u = r - 2 * ii;
                if (0 <= u && u < 8) {
                    const float a0 = H0[u], a1 = H1[u];
                    acc[ii][0][0] += a0 * h00;
                    acc[ii][0][1] += a0 * h10;
                    acc[ii][0][2] += a1 * h00;
                    acc[ii][0][3] += a1 * h10;
                    acc[ii][1][0] += a0 * h01;
                    acc[ii][1][1] += a0 * h11;
                    acc[ii][1][2] += a1 * h01;
                    acc[ii][1][3] += a1 * h11;
                }
            }
        }
    }

#pragma unroll
    for (int ii = 0; ii < 2; ++ii)
#pragma unroll
        for (int jj = 0; jj < 2; ++jj) {
            const int oh = 2 * i + ii, ow = 2 * j + jj;
            const int oidx = ((b * OH + oh) * OH + ow) * 64 + c;
            oLL[oidx] = acc[ii][jj][0];
            oLH[oidx] = acc[ii][jj][1];
            oHL[oidx] = acc[ii][jj][2];
            oHH[oidx] = acc[ii][jj][3];
        }
}

// ---------------------------------------------------------------------------
// Activation transpose: t[b,h,w,i] -> A'[w][i][b][h] (unchanged).
// ---------------------------------------------------------------------------
template<int HD>
__global__ __launch_bounds__(256) void act_tr(const float* __restrict__ in,
                                              float* __restrict__ outp)
{
    __shared__ float Ld[64][HD + 1];
    const int w = blockIdx.x;
    const int b = blockIdx.y;
    const int t = threadIdx.x;

    {   // read: lane = i (dense 256B per (b,h,w))
        const int i = t & 63;
        const int hq = t >> 6;
#pragma unroll
        for (int s = 0; s < HD / 4; ++s) {
            const int h = hq * (HD / 4) + s;
            Ld[i][h] = in[((size_t)(b * HD + h) * HD + w) * 64 + i];
        }
    }
    __syncthreads();
    {   // write: lane = h (dense per (w,i,b))
        const int h = t & (HD - 1);
        const int iq = t / HD;
        constexpr int NIQ = 256 / HD;
#pragma unroll
        for (int s = 0; s < 64 / NIQ; ++s) {
            const int i = s * NIQ + iq;
            outp[((size_t)(w * 64 + i) * 16 + b) * HD + h] = Ld[i][h];
        }
    }
}

// ---------------------------------------------------------------------------
// Local conv v9: pure-register GEMM, every global request 256B-dense.
// out[b,h,w,o] = sum_i A'[w][i][b][h] * W[i,o,w,h]
// Block tile: (WPB w) x HD h x OT o x 16 b, with HD*WPB == 64 so a wave's
// 64 lanes span a full contiguous 256B weight run. No LDS, no barriers:
// compiler overlaps next chunk's loads with current FMAs.
// Thread = (hc, wq, r): acc = 4 b x OT o. XCD-chunked 1D grid keeps og/w
// neighbors (which share act panels / weight rows) on the same XCD L2.
// ---------------------------------------------------------------------------
template<int HD, int OT, int WPB>
__global__ __launch_bounds__(256) void local_conv_v9(
    const float* __restrict__ a0, const float* __restrict__ a1,
    const float* __restrict__ a2, const float* __restrict__ a3,
    const float* __restrict__ w0, const float* __restrict__ w1,
    const float* __restrict__ w2, const float* __restrict__ w3,
    float* __restrict__ o0, float* __restrict__ o1,
    float* __restrict__ o2, float* __restrict__ o3)
{
    constexpr int WH   = HD * HD;
    constexpr int OGN  = 64 / OT;       // o-groups
    constexpr int WPN  = HD / WPB;      // w-panels
    constexpr int PERZ = WPN * OGN;
    constexpr int NB   = 4;             // b per thread

    // bijective XCD-chunked swizzle (grid % 8 == 0)
    const int nwg = gridDim.x;
    const int hb  = blockIdx.x;
    const int l   = (hb & 7) * (nwg >> 3) + (hb >> 3);

    const int z   = l / PERZ;
    const int rem = l - z * PERZ;
    const int wp  = rem / OGN;
    const int og  = rem - wp * OGN;

    const float* act = (z == 0) ? a0 : (z == 1) ? a1 : (z == 2) ? a2 : a3;
    const float* wgt = (z == 0) ? w0 : (z == 1) ? w1 : (z == 2) ? w2 : w3;
    float*       out = (z == 0) ? o0 : (z == 1) ? o1 : (z == 2) ? o2 : o3;

    const int t  = threadIdx.x;
    const int hc = t % HD;
    const int wq = (t / HD) % WPB;
    const int r  = t / (HD * WPB);      // wave index 0..3
    const int b0 = r * NB;
    const int wbase = wp * WPB + wq;

    const float* wpp = wgt + (size_t)(og * OT) * WH + wbase * HD + hc;
    const float* ap  = act + ((size_t)(wbase * 64) * 16 + b0) * HD + hc;

    float acc[NB][OT];
#pragma unroll
    for (int j = 0; j < NB; ++j)
#pragma unroll
        for (int q = 0; q < OT; ++q) acc[j][q] = 0.f;

    for (int ch = 0; ch < 32; ++ch) {
        const int i0 = ch * 2;
        float wr[2][OT];
        float ar[2][NB];
#pragma unroll
        for (int ii = 0; ii < 2; ++ii) {
#pragma unroll
            for (int q = 0; q < OT; ++q)
                wr[ii][q] = wpp[(size_t)((i0 + ii) * 64 + q) * WH];
#pragma unroll
            for (int j = 0; j < NB; ++j)
                ar[ii][j] = ap[(size_t)((i0 + ii) * 16 + j) * HD];
        }
#pragma unroll
        for (int ii = 0; ii < 2; ++ii)
#pragma unroll
            for (int j = 0; j < NB; ++j) {
                const float a = ar[ii][j];
#pragma unroll
                for (int q = 0; q < OT; ++q)
                    acc[j][q] += a * wr[ii][q];
            }
    }

    // direct stores: OT-float runs; og-siblings on the same XCD merge in L2
#pragma unroll
    for (int j = 0; j < NB; ++j) {
        const int b = b0 + j;
        float* op = out + ((size_t)(b * HD + hc) * HD + wbase) * 64 + og * OT;
#pragma unroll
        for (int q4 = 0; q4 < OT / 4; ++q4) {
            float4 v = make_float4(acc[j][q4 * 4 + 0], acc[j][q4 * 4 + 1],
                                   acc[j][q4 * 4 + 2], acc[j][q4 * 4 + 3]);
            *(float4*)(op + q4 * 4) = v;
        }
    }
}

// ---------------------------------------------------------------------------
// Inverse DWT, 2x2-output-tiled + separable (unchanged).
// ---------------------------------------------------------------------------
template<int HOUT>
__global__ __launch_bounds__(256) void inv_dwt(const float* __restrict__ yLL,
                                               const float* __restrict__ yLH,
                                               const float* __restrict__ yHL,
                                               const float* __restrict__ yHH,
                                               float* __restrict__ out)
{
    constexpr int HS = HOUT / 2;
    const int tid = threadIdx.x;
    const int c = tid & 63;
    const int s = blockIdx.x * 4 + (tid >> 6);
    const int j = s % HS;
    const int i = (s / HS) % HS;
    const int b = s / (HS * HS);

    float Pe[4] = {0.f, 0.f, 0.f, 0.f}, Po[4] = {0.f, 0.f, 0.f, 0.f};
    float Qe[4] = {0.f, 0.f, 0.f, 0.f}, Qo[4] = {0.f, 0.f, 0.f, 0.f};

#pragma unroll
    for (int ku = 0; ku < 4; ++ku) {
        const int m = i - 1 + ku;
        if ((unsigned)m < (unsigned)HS) {
            const float a0e = G0[1 + 2 * ku], a0o = G0[2 * ku];
            const float a1e = G1[1 + 2 * ku], a1o = G1[2 * ku];
            const int rowoff = (b * HS + m) * HS;
#pragma unroll
            for (int kv = 0; kv < 4; ++kv) {
                const int n = j - 1 + kv;
                if ((unsigned)n < (unsigned)HS) {
                    const int idx = (rowoff + n) * 64 + c;
                    const float yll = yLL[idx], ylh = yLH[idx];
                    const float yhl = yHL[idx], yhh = yHH[idx];
                    Pe[kv] += a0e * yll + a1e * yhl;
                    Po[kv] += a0o * yll + a1o * yhl;
                    Qe[kv] += a0e * ylh + a1e * yhh;
                    Qo[kv] += a0o * ylh + a1o * yhh;
                }
            }
        }
    }

    float o00 = 0.f, o01 = 0.f, o10 = 0.f, o11 = 0.f;
#pragma unroll
    for (int kv = 0; kv < 4; ++kv) {
        const float b0e = G0[1 + 2 * kv], b0o = G0[2 * kv];
        const float b1e = G1[1 + 2 * kv], b1o = G1[2 * kv];
        o00 += b0e * Pe[kv] + b1e * Qe[kv];
        o01 += b0o * Pe[kv] + b1o * Qe[kv];
        o10 += b0e * Po[kv] + b1e * Qo[kv];
        o11 += b0o * Po[kv] + b1o * Qo[kv];
    }

    const int h0 = 2 * i, w0 = 2 * j;
    const int base = ((b * HOUT + h0) * HOUT + w0) * 64 + c;
    out[base] = o00;
    out[base + 64] = o01;
    out[base + HOUT * 64] = o10;
    out[base + HOUT * 64 + 64] = o11;
}

// ---------------------------------------------------------------------------
extern "C" void kernel_launch(void* const* d_in, const int* in_sizes, int n_in,
                              void* d_out, int out_size, void* d_ws, size_t ws_size,
                              hipStream_t stream)
{
    const float* x    = (const float*)d_in[0];
    const float* wLL  = (const float*)d_in[1];
    const float* wLH0 = (const float*)d_in[2];
    const float* wHL0 = (const float*)d_in[3];
    const float* wHH0 = (const float*)d_in[4];
    const float* wLH1 = (const float*)d_in[5];
    const float* wHL1 = (const float*)d_in[6];
    const float* wHH1 = (const float*)d_in[7];
    float* out = (float*)d_out;
    float* ws  = (float*)d_ws;

    const int S0 = 16 * 64 * 64 * 64;   // level-0 subband elems (4S1 = S0)
    const int S1 = 16 * 32 * 32 * 64;   // level-1 subband elems

    // d_out doubles as scratch: first c0{LL,LH,HL,HH}, then transposed acts.
    float* c0 = out;                    // 4*S0
    float* A0 = out;                    // 3*S0: LH',HL',HH' (reuse dead c0 slots)
    float* A1 = out + 3 * S0;           // 4*S1: LL',LH',HL',HH'

    float* c1 = ws;                     // 4*S1, later reused as r1
    float* t0 = ws + 4 * S1;            // 3*S0
    float* t1 = ws + 4 * S1 + 3 * S0;   // 3*S1
    float* yA = ws + 7 * S1 + 3 * S0;   // S1
    float* r1 = ws;                     // S0, overwrites dead c1

    // 1) level-0 forward DWT: x -> c0 (in d_out)
    fwd_dwt<128><<<16 * 32 * 32 / 4, 256, 0, stream>>>(x, c0, c0 + S0, c0 + 2 * S0, c0 + 3 * S0);

    // 2) level-1 forward DWT: c0LL -> c1 (ws)
    fwd_dwt<64><<<16 * 16 * 16 / 4, 256, 0, stream>>>(c0,
        c1 + 0 * S1, c1 + 1 * S1, c1 + 2 * S1, c1 + 3 * S1);

    // 3) transpose level-0 details into dead c0 slots (sequential chain)
    act_tr<64><<<dim3(64, 16), 256, 0, stream>>>(c0 + 1 * S0, A0 + 0 * S0);  // LH'
    act_tr<64><<<dim3(64, 16), 256, 0, stream>>>(c0 + 2 * S0, A0 + 1 * S0);  // HL'
    act_tr<64><<<dim3(64, 16), 256, 0, stream>>>(c0 + 3 * S0, A0 + 2 * S0);  // HH'

    // 4) transpose level-1 subbands
    act_tr<32><<<dim3(32, 16), 256, 0, stream>>>(c1 + 0 * S1, A1 + 0 * S1);  // LL'
    act_tr<32><<<dim3(32, 16), 256, 0, stream>>>(c1 + 1 * S1, A1 + 1 * S1);  // LH'
    act_tr<32><<<dim3(32, 16), 256, 0, stream>>>(c1 + 2 * S1, A1 + 2 * S1);  // HL'
    act_tr<32><<<dim3(32, 16), 256, 0, stream>>>(c1 + 3 * S1, A1 + 3 * S1);  // HH'

    // 5) local conv level-0: HD=64, OT=8, WPB=1 -> grid 3*64*8 = 1536
    local_conv_v9<64, 8, 1><<<1536, 256, 0, stream>>>(
        A0 + 0 * S0, A0 + 1 * S0, A0 + 2 * S0, nullptr,
        wLH0, wHL0, wHH0, nullptr,
        t0 + 0 * S0, t0 + 1 * S0, t0 + 2 * S0, nullptr);

    // 6) local conv level-1: HD=32, OT=4, WPB=2 -> grid 4*16*16 = 1024
    local_conv_v9<32, 4, 2><<<1024, 256, 0, stream>>>(
        A1 + 1 * S1, A1 + 2 * S1, A1 + 3 * S1, A1 + 0 * S1,
        wLH1, wHL1, wHH1, wLL,
        t1 + 0 * S1, t1 + 1 * S1, t1 + 2 * S1, yA);

    // 7) inverse level-1: (yA, t1) -> r1
    inv_dwt<64><<<16 * 32 * 32 / 4, 256, 0, stream>>>(
        yA, t1 + 0 * S1, t1 + 1 * S1, t1 + 2 * S1, r1);

    // 8) inverse level-0: (r1, t0) -> out
    inv_dwt<128><<<16 * 64 * 64 / 4, 256, 0, stream>>>(
        r1, t0 + 0 * S0, t0 + 1 * S0, t0 + 2 * S0, out);
}

// Round 11
// 307.256 us; speedup vs baseline: 1.1622x; 1.0619x over previous
//
#include <hip/hip_runtime.h>

// Analysis filters
__device__ __constant__ float H0[8] = { 0.0322231f, -0.01260397f, -0.09921954f,  0.2978578f,
                                        0.80373875f, 0.49761867f, -0.02963553f, -0.07576571f};
__device__ __constant__ float H1[8] = { 0.07576571f, -0.02963553f, -0.49761867f, 0.80373875f,
                                       -0.2978578f, -0.09921954f,  0.01260397f,  0.0322231f};
// Synthesis filters g0 = reverse(h0), g1 = reverse(h1)
__device__ __constant__ float G0[8] = {-0.07576571f, -0.02963553f,  0.49761867f, 0.80373875f,
                                        0.2978578f,  -0.09921954f, -0.01260397f, 0.0322231f};
__device__ __constant__ float G1[8] = { 0.0322231f,   0.01260397f, -0.09921954f, -0.2978578f,
                                        0.80373875f, -0.49761867f, -0.02963553f, 0.07576571f};

// ---------------------------------------------------------------------------
// Forward DWT, 2x2-output-tiled + separable (unchanged).
// ---------------------------------------------------------------------------
template<int HIN>
__global__ __launch_bounds__(256) void fwd_dwt(const float* __restrict__ in,
                                               float* __restrict__ oLL, float* __restrict__ oLH,
                                               float* __restrict__ oHL, float* __restrict__ oHH)
{
    constexpr int OH = HIN / 2;
    constexpr int TQ = OH / 2;
    const int tid = threadIdx.x;
    const int c = tid & 63;
    const int s = blockIdx.x * 4 + (tid >> 6);
    const int j = s % TQ;
    const int i = (s / TQ) % TQ;
    const int b = s / (TQ * TQ);

    float acc[2][2][4];
#pragma unroll
    for (int a = 0; a < 2; ++a)
#pragma unroll
        for (int d = 0; d < 2; ++d)
#pragma unroll
            for (int k = 0; k < 4; ++k) acc[a][d][k] = 0.f;

    const int iw0 = 4 * j - 3;
#pragma unroll
    for (int r = 0; r < 10; ++r) {
        const int ih = 4 * i + r - 3;
        if ((unsigned)ih < (unsigned)HIN) {
            const float* row = in + ((b * HIN + ih) * HIN) * 64 + c;
            float xv[10];
#pragma unroll
            for (int v = 0; v < 10; ++v) {
                const int iw = iw0 + v;
                xv[v] = ((unsigned)iw < (unsigned)HIN) ? row[iw * 64] : 0.f;
            }
            float h00 = 0.f, h01 = 0.f, h10 = 0.f, h11 = 0.f;
#pragma unroll
            for (int v = 0; v < 8; ++v) {
                h00 += H0[v] * xv[v];
                h10 += H1[v] * xv[v];
                h01 += H0[v] * xv[v + 2];
                h11 += H1[v] * xv[v + 2];
            }
#pragma unroll
            for (int ii = 0; ii < 2; ++ii) {
                const int u = r - 2 * ii;
                if (0 <= u && u < 8) {
                    const float a0 = H0[u], a1 = H1[u];
                    acc[ii][0][0] += a0 * h00;
                    acc[ii][0][1] += a0 * h10;
                    acc[ii][0][2] += a1 * h00;
                    acc[ii][0][3] += a1 * h10;
                    acc[ii][1][0] += a0 * h01;
                    acc[ii][1][1] += a0 * h11;
                    acc[ii][1][2] += a1 * h01;
                    acc[ii][1][3] += a1 * h11;
                }
            }
        }
    }

#pragma unroll
    for (int ii = 0; ii < 2; ++ii)
#pragma unroll
        for (int jj = 0; jj < 2; ++jj) {
            const int oh = 2 * i + ii, ow = 2 * j + jj;
            const int oidx = ((b * OH + oh) * OH + ow) * 64 + c;
            oLL[oidx] = acc[ii][jj][0];
            oLH[oidx] = acc[ii][jj][1];
            oHL[oidx] = acc[ii][jj][2];
            oHH[oidx] = acc[ii][jj][3];
        }
}

// ---------------------------------------------------------------------------
// Activation transpose: t[b,h,w,i] -> A'[w][i][b][h] (unchanged).
// ---------------------------------------------------------------------------
template<int HD>
__global__ __launch_bounds__(256) void act_tr(const float* __restrict__ in,
                                              float* __restrict__ outp)
{
    __shared__ float Ld[64][HD + 1];
    const int w = blockIdx.x;
    const int b = blockIdx.y;
    const int t = threadIdx.x;

    {   // read: lane = i (dense 256B per (b,h,w))
        const int i = t & 63;
        const int hq = t >> 6;
#pragma unroll
        for (int s = 0; s < HD / 4; ++s) {
            const int h = hq * (HD / 4) + s;
            Ld[i][h] = in[((size_t)(b * HD + h) * HD + w) * 64 + i];
        }
    }
    __syncthreads();
    {   // write: lane = h (dense per (w,i,b))
        const int h = t & (HD - 1);
        const int iq = t / HD;
        constexpr int NIQ = 256 / HD;
#pragma unroll
        for (int s = 0; s < 64 / NIQ; ++s) {
            const int i = s * NIQ + iq;
            outp[((size_t)(w * 64 + i) * 16 + b) * HD + h] = Ld[i][h];
        }
    }
}

// ---------------------------------------------------------------------------
// Local conv v10: w-slab register GEMM with >=1KB-contiguous weight reads.
// out[b,h,w,o] = sum_i A'[w][i][b][h] * W[i,o,w,h]
// Block tile: WSL w x HD h x OT o x NBT b  (WSL*HD == 256).
// Per (i,o) the block reads W[i][o][wq*WSL : +WSL][*] = WSL*HD*4B = 1KB
// CONTIGUOUS (the block's waves issue adjacent 256B runs in lockstep) ->
// full DRAM-row utilization, unlike the 256B/16KB-stride pattern of v7-v9.
// Grid order: ((z, wq) outer) x (og, bg inner) with bijective XCD chunking:
// each (z,wq) group of OGN*BGN blocks is co-resident on ONE XCD ->
//  - acts (1MB slab) L2-served across og/bg siblings,
//  - bg-duplicated weight reads L2-served, HBM reads weights exactly once,
//  - 32B o-run stores: og-siblings dirty complementary line halves in the
//    same L2 -> full-line write-back (no write amplification).
// Thread = (w_l, hc): one (w,h) site, acc = NBT b x OT o registers.
// ---------------------------------------------------------------------------
template<int HD, int WSL, int OT, int NBT>
__global__ __launch_bounds__(256) void local_conv_v10(
    const float* __restrict__ a0, const float* __restrict__ a1,
    const float* __restrict__ a2, const float* __restrict__ a3,
    const float* __restrict__ w0, const float* __restrict__ w1,
    const float* __restrict__ w2, const float* __restrict__ w3,
    float* __restrict__ o0, float* __restrict__ o1,
    float* __restrict__ o2, float* __restrict__ o3)
{
    constexpr int WH   = HD * HD;
    constexpr int OGN  = 64 / OT;
    constexpr int BGN  = 16 / NBT;
    constexpr int PERZ = (HD / WSL) * OGN * BGN;

    // bijective XCD-chunked swizzle (grid % 8 == 0)
    const int nwg = gridDim.x;
    const int hb  = blockIdx.x;
    const int l   = (hb & 7) * (nwg >> 3) + (hb >> 3);

    const int z  = l / PERZ;
    int rem      = l - z * PERZ;
    const int wq = rem / (OGN * BGN);
    rem         -= wq * (OGN * BGN);
    const int og = rem / BGN;
    const int bg = rem - og * BGN;

    const float* act = (z == 0) ? a0 : (z == 1) ? a1 : (z == 2) ? a2 : a3;
    const float* wgt = (z == 0) ? w0 : (z == 1) ? w1 : (z == 2) ? w2 : w3;
    float*       out = (z == 0) ? o0 : (z == 1) ? o1 : (z == 2) ? o2 : o3;

    const int t   = threadIdx.x;
    const int w_l = t / HD;
    const int hc  = t % HD;
    const int w   = wq * WSL + w_l;
    const int b0  = bg * NBT;
    const int o0g = og * OT;

    const float* wp = wgt + (size_t)o0g * WH + w * HD + hc;
    const float* ap = act + ((size_t)(w * 64) * 16 + b0) * HD + hc;

    float acc[NBT][OT];
#pragma unroll
    for (int j = 0; j < NBT; ++j)
#pragma unroll
        for (int q = 0; q < OT; ++q) acc[j][q] = 0.f;

    for (int ch = 0; ch < 32; ++ch) {
        const int i0 = ch * 2;
        float wr[2][OT];
        float ar[2][NBT];
#pragma unroll
        for (int ii = 0; ii < 2; ++ii) {
#pragma unroll
            for (int q = 0; q < OT; ++q)
                wr[ii][q] = wp[(size_t)((i0 + ii) * 64 + q) * WH];
#pragma unroll
            for (int j = 0; j < NBT; ++j)
                ar[ii][j] = ap[(size_t)((i0 + ii) * 16 + j) * HD];
        }
#pragma unroll
        for (int ii = 0; ii < 2; ++ii)
#pragma unroll
            for (int j = 0; j < NBT; ++j) {
                const float a = ar[ii][j];
#pragma unroll
                for (int q = 0; q < OT; ++q)
                    acc[j][q] += a * wr[ii][q];
            }
    }

    // direct stores: OT-float (32B) runs; og-siblings co-resident on the same
    // XCD L2 complete each 128B line before write-back.
#pragma unroll
    for (int j = 0; j < NBT; ++j) {
        const int b = b0 + j;
        float* op = out + ((size_t)(b * HD + hc) * HD + w) * 64 + o0g;
#pragma unroll
        for (int q4 = 0; q4 < OT / 4; ++q4) {
            float4 v = make_float4(acc[j][q4 * 4 + 0], acc[j][q4 * 4 + 1],
                                   acc[j][q4 * 4 + 2], acc[j][q4 * 4 + 3]);
            *(float4*)(op + q4 * 4) = v;
        }
    }
}

// ---------------------------------------------------------------------------
// Inverse DWT, 2x2-output-tiled + separable (unchanged).
// ---------------------------------------------------------------------------
template<int HOUT>
__global__ __launch_bounds__(256) void inv_dwt(const float* __restrict__ yLL,
                                               const float* __restrict__ yLH,
                                               const float* __restrict__ yHL,
                                               const float* __restrict__ yHH,
                                               float* __restrict__ out)
{
    constexpr int HS = HOUT / 2;
    const int tid = threadIdx.x;
    const int c = tid & 63;
    const int s = blockIdx.x * 4 + (tid >> 6);
    const int j = s % HS;
    const int i = (s / HS) % HS;
    const int b = s / (HS * HS);

    float Pe[4] = {0.f, 0.f, 0.f, 0.f}, Po[4] = {0.f, 0.f, 0.f, 0.f};
    float Qe[4] = {0.f, 0.f, 0.f, 0.f}, Qo[4] = {0.f, 0.f, 0.f, 0.f};

#pragma unroll
    for (int ku = 0; ku < 4; ++ku) {
        const int m = i - 1 + ku;
        if ((unsigned)m < (unsigned)HS) {
            const float a0e = G0[1 + 2 * ku], a0o = G0[2 * ku];
            const float a1e = G1[1 + 2 * ku], a1o = G1[2 * ku];
            const int rowoff = (b * HS + m) * HS;
#pragma unroll
            for (int kv = 0; kv < 4; ++kv) {
                const int n = j - 1 + kv;
                if ((unsigned)n < (unsigned)HS) {
                    const int idx = (rowoff + n) * 64 + c;
                    const float yll = yLL[idx], ylh = yLH[idx];
                    const float yhl = yHL[idx], yhh = yHH[idx];
                    Pe[kv] += a0e * yll + a1e * yhl;
                    Po[kv] += a0o * yll + a1o * yhl;
                    Qe[kv] += a0e * ylh + a1e * yhh;
                    Qo[kv] += a0o * ylh + a1o * yhh;
                }
            }
        }
    }

    float o00 = 0.f, o01 = 0.f, o10 = 0.f, o11 = 0.f;
#pragma unroll
    for (int kv = 0; kv < 4; ++kv) {
        const float b0e = G0[1 + 2 * kv], b0o = G0[2 * kv];
        const float b1e = G1[1 + 2 * kv], b1o = G1[2 * kv];
        o00 += b0e * Pe[kv] + b1e * Qe[kv];
        o01 += b0o * Pe[kv] + b1o * Qe[kv];
        o10 += b0e * Po[kv] + b1e * Qo[kv];
        o11 += b0o * Po[kv] + b1o * Qo[kv];
    }

    const int h0 = 2 * i, w0 = 2 * j;
    const int base = ((b * HOUT + h0) * HOUT + w0) * 64 + c;
    out[base] = o00;
    out[base + 64] = o01;
    out[base + HOUT * 64] = o10;
    out[base + HOUT * 64 + 64] = o11;
}

// ---------------------------------------------------------------------------
extern "C" void kernel_launch(void* const* d_in, const int* in_sizes, int n_in,
                              void* d_out, int out_size, void* d_ws, size_t ws_size,
                              hipStream_t stream)
{
    const float* x    = (const float*)d_in[0];
    const float* wLL  = (const float*)d_in[1];
    const float* wLH0 = (const float*)d_in[2];
    const float* wHL0 = (const float*)d_in[3];
    const float* wHH0 = (const float*)d_in[4];
    const float* wLH1 = (const float*)d_in[5];
    const float* wHL1 = (const float*)d_in[6];
    const float* wHH1 = (const float*)d_in[7];
    float* out = (float*)d_out;
    float* ws  = (float*)d_ws;

    const int S0 = 16 * 64 * 64 * 64;   // level-0 subband elems (4S1 = S0)
    const int S1 = 16 * 32 * 32 * 64;   // level-1 subband elems

    // d_out doubles as scratch: first c0{LL,LH,HL,HH}, then transposed acts.
    float* c0 = out;                    // 4*S0
    float* A0 = out;                    // 3*S0: LH',HL',HH' (reuse dead c0 slots)
    float* A1 = out + 3 * S0;           // 4*S1: LL',LH',HL',HH'

    float* c1 = ws;                     // 4*S1, later reused as r1
    float* t0 = ws + 4 * S1;            // 3*S0
    float* t1 = ws + 4 * S1 + 3 * S0;   // 3*S1
    float* yA = ws + 7 * S1 + 3 * S0;   // S1
    float* r1 = ws;                     // S0, overwrites dead c1

    // 1) level-0 forward DWT: x -> c0 (in d_out)
    fwd_dwt<128><<<16 * 32 * 32 / 4, 256, 0, stream>>>(x, c0, c0 + S0, c0 + 2 * S0, c0 + 3 * S0);

    // 2) level-1 forward DWT: c0LL -> c1 (ws)
    fwd_dwt<64><<<16 * 16 * 16 / 4, 256, 0, stream>>>(c0,
        c1 + 0 * S1, c1 + 1 * S1, c1 + 2 * S1, c1 + 3 * S1);

    // 3) transpose level-0 details into dead c0 slots (sequential chain)
    act_tr<64><<<dim3(64, 16), 256, 0, stream>>>(c0 + 1 * S0, A0 + 0 * S0);  // LH'
    act_tr<64><<<dim3(64, 16), 256, 0, stream>>>(c0 + 2 * S0, A0 + 1 * S0);  // HL'
    act_tr<64><<<dim3(64, 16), 256, 0, stream>>>(c0 + 3 * S0, A0 + 2 * S0);  // HH'

    // 4) transpose level-1 subbands
    act_tr<32><<<dim3(32, 16), 256, 0, stream>>>(c1 + 0 * S1, A1 + 0 * S1);  // LL'
    act_tr<32><<<dim3(32, 16), 256, 0, stream>>>(c1 + 1 * S1, A1 + 1 * S1);  // LH'
    act_tr<32><<<dim3(32, 16), 256, 0, stream>>>(c1 + 2 * S1, A1 + 2 * S1);  // HL'
    act_tr<32><<<dim3(32, 16), 256, 0, stream>>>(c1 + 3 * S1, A1 + 3 * S1);  // HH'

    // 5) local conv level-0: HD=64, 4w x 8o x 8b -> grid 3z*16wq*8og*2bg = 768
    local_conv_v10<64, 4, 8, 8><<<768, 256, 0, stream>>>(
        A0 + 0 * S0, A0 + 1 * S0, A0 + 2 * S0, nullptr,
        wLH0, wHL0, wHH0, nullptr,
        t0 + 0 * S0, t0 + 1 * S0, t0 + 2 * S0, nullptr);

    // 6) local conv level-1: HD=32, 8w x 8o x 4b -> grid 4z*4wq*8og*4bg = 512
    local_conv_v10<32, 8, 8, 4><<<512, 256, 0, stream>>>(
        A1 + 1 * S1, A1 + 2 * S1, A1 + 3 * S1, A1 + 0 * S1,
        wLH1, wHL1, wHH1, wLL,
        t1 + 0 * S1, t1 + 1 * S1, t1 + 2 * S1, yA);

    // 7) inverse level-1: (yA, t1) -> r1
    inv_dwt<64><<<16 * 32 * 32 / 4, 256, 0, stream>>>(
        yA, t1 + 0 * S1, t1 + 1 * S1, t1 + 2 * S1, r1);

    // 8) inverse level-0: (r1, t0) -> out
    inv_dwt<128><<<16 * 64 * 64 / 4, 256, 0, stream>>>(
        r1, t0 + 0 * S0, t0 + 1 * S0, t0 + 2 * S0, out);
}